// Round 3
// baseline (237.420 us; speedup 1.0000x reference)
//
#include <hip/hip_runtime.h>
#include <hip/hip_bf16.h>
#include <math.h>

// Problem constants
#define BROWS 16384
#define IN_DIM 128
#define HID 512
#define ATT 256
#define KTOT 896          // IN_DIM + HID + ATT
#define KC_TOT 112        // KTOT / 8

typedef __bf16 bf16x8 __attribute__((ext_vector_type(8)));
typedef float f32x4 __attribute__((ext_vector_type(4)));

// ---------------------------------------------------------------------------
// Kernel 1: pack augmented weights -> B_stage[jt(8)][kc(112)][nl(192)][8] bf16.
// nl = jg*48 + type*16 + j16 ; jg in [0,4), type 0=gate 1=dyn 2=tau.
// j = jt*64 + jg*16 + j16. tau rows nonzero only for k in [128,640).
// ---------------------------------------------------------------------------
__device__ __forceinline__ float softplus_f(float x) {
    return fmaxf(x, 0.0f) + log1pf(__expf(-fabsf(x)));
}

__global__ void pack_B(const float* __restrict__ W_gd, const float* __restrict__ W_tau,
                       const float* __restrict__ gleak, const float* __restrict__ cm,
                       __hip_bfloat16* __restrict__ B_stage, float* __restrict__ dconst) {
    const int cid = blockIdx.x * 256 + threadIdx.x;   // 672*256 = 172032 exactly
    if (cid < HID) {
        dconst[cid] = softplus_f(cm[cid]) + softplus_f(gleak[cid]) + 1e-6f;
    }
    const int nl = cid % 192;
    const int kc = (cid / 192) % KC_TOT;
    const int jt = cid / (192 * KC_TOT);
    const int jg = nl / 48, type = (nl % 48) / 16, j16 = nl % 16;
    const int j = jt * 64 + jg * 16 + j16;
    const int k0 = kc * 8;

    float v[8];
    if (type == 0) {
        const float* s = W_gd + (size_t)j * KTOT + k0;
        #pragma unroll
        for (int i = 0; i < 8; ++i) v[i] = s[i];
    } else if (type == 1) {
        const float* s = W_gd + (size_t)(HID + j) * KTOT + k0;
        #pragma unroll
        for (int i = 0; i < 8; ++i) v[i] = s[i];
    } else {
        if (k0 >= IN_DIM && k0 < IN_DIM + HID) {
            const float* s = W_tau + (size_t)j * HID + (k0 - IN_DIM);
            #pragma unroll
            for (int i = 0; i < 8; ++i) v[i] = s[i];
        } else {
            #pragma unroll
            for (int i = 0; i < 8; ++i) v[i] = 0.0f;
        }
    }
    union { __hip_bfloat16 hh[8]; uint4 u; } p;
    #pragma unroll
    for (int i = 0; i < 8; ++i) p.hh[i] = __float2bfloat16(v[i]);
    *(uint4*)(B_stage + (size_t)cid * 8) = p.u;
}

// ---------------------------------------------------------------------------
// Kernel 2: fused convert+GEMM+epilogue.
// A (fp32, [x|h|ctx]) is loaded directly, converted to bf16 in-register, and
// ds_written into LDS with an XOR bank swizzle (mi ^ kc). fp32 loads for step
// ks+1 are issued during step ks's MFMA phase (register prefetch).
// Block tile: 128(M) x 64(j) x {gate,dyn,tau}. 4 waves (2M x 2Jg). BK=64.
// Grid: 1024 blocks (mt = bx & 127 -> A-tile siblings co-XCD). 256 threads.
// LDS: As = 8kc x 128mi x 16B = 16KB ; Bs = 8kc x 192nl x 16B = 24KB.
// ---------------------------------------------------------------------------
__device__ __forceinline__ void slab_src(int ks, const float* x, const float* h,
                                         const float* c, const float*& src,
                                         int& rs, int& c0) {
    if (ks < 2)       { src = x; rs = IN_DIM; c0 = ks * 64; }
    else if (ks < 10) { src = h; rs = HID;    c0 = (ks - 2) * 64; }
    else              { src = c; rs = ATT;    c0 = (ks - 10) * 64; }
}

__global__ __launch_bounds__(256, 3) void ltc_gemm(
    const float* __restrict__ x, const float* __restrict__ h_ltc,
    const float* __restrict__ ctx, const __hip_bfloat16* __restrict__ B_stage,
    const float* __restrict__ b_gd, const float* __restrict__ b_tau,
    const float* __restrict__ dconst, float* __restrict__ out) {

    __shared__ __attribute__((aligned(16))) char smem[16384 + 24576];
    char* As = smem;
    char* Bs = smem + 16384;

    const int bx = blockIdx.x;
    const int mt = bx & 127;    // A-tile id; bx % 8 == mt % 8 -> co-XCD siblings
    const int jt = bx >> 7;     // 0..7
    const int tid = threadIdx.x;
    const int wave = tid >> 6, lane = tid & 63;
    const int wm = wave >> 1;   // 0..1  M half (64 rows)
    const int wj = wave & 1;    // 0..1  jg pair (32 j)
    const int q = lane >> 4, t = lane & 15;

    // A staging role: chunk (kc8, mi0 + 32r) for r<4
    const int kc8 = tid & 7;    // k-chunk in slab
    const int mi0 = tid >> 3;   // 0..31

    f32x4 accg[2][4], accd[2][4], acct[2][4];
    #pragma unroll
    for (int g = 0; g < 2; ++g)
        #pragma unroll
        for (int i = 0; i < 4; ++i) {
            accg[g][i] = (f32x4)0.0f; accd[g][i] = (f32x4)0.0f; acct[g][i] = (f32x4)0.0f;
        }

    // B staging: 24 chunks of 1KB, wave handles {wave+4r, r<6} via global_load_lds
    const __hip_bfloat16* bSrc[6]; char* bDst[6];
    #pragma unroll
    for (int r = 0; r < 6; ++r) {
        int c = wave + 4 * r;
        bSrc[r] = B_stage + (size_t)jt * (KC_TOT * 1536) + c * 512 + lane * 8;
        bDst[r] = Bs + c * 1024;
    }

    // Register prefetch of A slab ks=0 (fp32)
    float4 pf[4][2];
    {
        const float* src; int rs, c0;
        slab_src(0, x, h_ltc, ctx, src, rs, c0);
        #pragma unroll
        for (int r = 0; r < 4; ++r) {
            const float* p = src + (size_t)(mt * 128 + mi0 + 32 * r) * rs + c0 + kc8 * 8;
            pf[r][0] = *(const float4*)p;
            pf[r][1] = *(const float4*)(p + 4);
        }
    }

    for (int ks = 0; ks < 14; ++ks) {
        // Stage A: convert prefetched fp32 -> bf16, ds_write_b128 (XOR swizzle)
        #pragma unroll
        for (int r = 0; r < 4; ++r) {
            union { __hip_bfloat16 hh[8]; uint4 u; } pk;
            pk.hh[0] = __float2bfloat16(pf[r][0].x);
            pk.hh[1] = __float2bfloat16(pf[r][0].y);
            pk.hh[2] = __float2bfloat16(pf[r][0].z);
            pk.hh[3] = __float2bfloat16(pf[r][0].w);
            pk.hh[4] = __float2bfloat16(pf[r][1].x);
            pk.hh[5] = __float2bfloat16(pf[r][1].y);
            pk.hh[6] = __float2bfloat16(pf[r][1].z);
            pk.hh[7] = __float2bfloat16(pf[r][1].w);
            const int mi = mi0 + 32 * r;
            *(uint4*)(As + ((kc8 * 128 + (mi ^ kc8)) << 4)) = pk.u;
        }
        // Stage B: async global->LDS
        #pragma unroll
        for (int r = 0; r < 6; ++r)
            __builtin_amdgcn_global_load_lds(
                (const __attribute__((address_space(1))) void*)bSrc[r],
                (__attribute__((address_space(3))) void*)bDst[r], 16, 0, 0);
        __syncthreads();   // drains ds_write (lgkm) + B loads (vmcnt)

        // Register-prefetch A slab ks+1 (overlaps with MFMA phase below)
        if (ks < 13) {
            const float* src; int rs, c0;
            slab_src(ks + 1, x, h_ltc, ctx, src, rs, c0);
            #pragma unroll
            for (int r = 0; r < 4; ++r) {
                const float* p = src + (size_t)(mt * 128 + mi0 + 32 * r) * rs + c0 + kc8 * 8;
                pf[r][0] = *(const float4*)p;
                pf[r][1] = *(const float4*)(p + 4);
            }
        }

        const bool tau_on = (ks >= 2 && ks < 10);  // k in [128,640)
        #pragma unroll
        for (int ko2 = 0; ko2 < 2; ++ko2) {
            const int kcl = ko2 * 4 + q;
            const char* ab = As + ((kcl * 128 + ((wm * 64 + t) ^ kcl)) << 4);
            bf16x8 a0 = *(const bf16x8*)(ab);
            bf16x8 a1 = *(const bf16x8*)(ab + 256);
            bf16x8 a2 = *(const bf16x8*)(ab + 512);
            bf16x8 a3 = *(const bf16x8*)(ab + 768);
            #pragma unroll
            for (int g = 0; g < 2; ++g) {
                const char* bb = Bs + (((kcl * 192) + wj * 96 + g * 48 + t) << 4);
                bf16x8 bg = *(const bf16x8*)(bb);
                bf16x8 bd = *(const bf16x8*)(bb + 256);
                accg[g][0] = __builtin_amdgcn_mfma_f32_16x16x32_bf16(a0, bg, accg[g][0], 0, 0, 0);
                accg[g][1] = __builtin_amdgcn_mfma_f32_16x16x32_bf16(a1, bg, accg[g][1], 0, 0, 0);
                accg[g][2] = __builtin_amdgcn_mfma_f32_16x16x32_bf16(a2, bg, accg[g][2], 0, 0, 0);
                accg[g][3] = __builtin_amdgcn_mfma_f32_16x16x32_bf16(a3, bg, accg[g][3], 0, 0, 0);
                accd[g][0] = __builtin_amdgcn_mfma_f32_16x16x32_bf16(a0, bd, accd[g][0], 0, 0, 0);
                accd[g][1] = __builtin_amdgcn_mfma_f32_16x16x32_bf16(a1, bd, accd[g][1], 0, 0, 0);
                accd[g][2] = __builtin_amdgcn_mfma_f32_16x16x32_bf16(a2, bd, accd[g][2], 0, 0, 0);
                accd[g][3] = __builtin_amdgcn_mfma_f32_16x16x32_bf16(a3, bd, accd[g][3], 0, 0, 0);
                if (tau_on) {
                    bf16x8 bt = *(const bf16x8*)(bb + 512);
                    acct[g][0] = __builtin_amdgcn_mfma_f32_16x16x32_bf16(a0, bt, acct[g][0], 0, 0, 0);
                    acct[g][1] = __builtin_amdgcn_mfma_f32_16x16x32_bf16(a1, bt, acct[g][1], 0, 0, 0);
                    acct[g][2] = __builtin_amdgcn_mfma_f32_16x16x32_bf16(a2, bt, acct[g][2], 0, 0, 0);
                    acct[g][3] = __builtin_amdgcn_mfma_f32_16x16x32_bf16(a3, bt, acct[g][3], 0, 0, 0);
                }
            }
        }
        #pragma unroll
        for (int r = 0; r < 6; ++r) bSrc[r] += 12288;   // 8 kc * 192 * 8
        __syncthreads();   // protect LDS before next stage
    }

    // Epilogue: bias + sigmoid/tanh/softplus + divide, fast-math intrinsics.
    const int row0 = mt * 128 + wm * 64 + q * 4;
    #pragma unroll
    for (int g = 0; g < 2; ++g) {
        const int j = jt * 64 + (wj * 2 + g) * 16 + t;
        const float bgj = b_gd[j];
        const float bdj = b_gd[HID + j];
        const float btj = b_tau[j];
        const float dcj = dconst[j];
        #pragma unroll
        for (int i = 0; i < 4; ++i) {
            #pragma unroll
            for (int r = 0; r < 4; ++r) {
                const int row = row0 + i * 16 + r;
                const float gv = accg[g][i][r] + bgj;
                const float dv = accd[g][i][r] + bdj;
                const float tp = acct[g][i][r] + btj;
                const float hv = h_ltc[(size_t)row * HID + j];
                const float sig = __builtin_amdgcn_rcpf(1.0f + __expf(-gv));
                const float th  = 1.0f - 2.0f * __builtin_amdgcn_rcpf(__expf(2.0f * dv) + 1.0f);
                const float tau = fmaxf(tp, 0.0f) + __logf(1.0f + __expf(-fabsf(tp)));
                out[(size_t)row * HID + j] = (sig * th - hv) * __builtin_amdgcn_rcpf(tau + dcj);
            }
        }
    }
}

// ---------------------------------------------------------------------------
extern "C" void kernel_launch(void* const* d_in, const int* in_sizes, int n_in,
                              void* d_out, int out_size, void* d_ws, size_t ws_size,
                              hipStream_t stream) {
    // setup_inputs order: t, h_ltc, x_t, context, W_gd, b_gd, W_tau, b_tau, gleak, cm
    const float* h_ltc = (const float*)d_in[1];
    const float* x_t   = (const float*)d_in[2];
    const float* ctx   = (const float*)d_in[3];
    const float* W_gd  = (const float*)d_in[4];
    const float* b_gd  = (const float*)d_in[5];
    const float* W_tau = (const float*)d_in[6];
    const float* b_tau = (const float*)d_in[7];
    const float* gleak = (const float*)d_in[8];
    const float* cm    = (const float*)d_in[9];

    char* ws = (char*)d_ws;
    __hip_bfloat16* B_stage = (__hip_bfloat16*)ws;      // 8*112*192*8*2 = 2,752,512 B
    float* dconst = (float*)(ws + 2752512);             // 2,048 B

    pack_B<<<672, 256, 0, stream>>>(W_gd, W_tau, gleak, cm, B_stage, dconst);
    ltc_gemm<<<1024, 256, 0, stream>>>(x_t, h_ltc, ctx, B_stage, b_gd, b_tau, dconst,
                                       (float*)d_out);
}

// Round 4
// 170.168 us; speedup vs baseline: 1.3952x; 1.3952x over previous
//
#include <hip/hip_runtime.h>
#include <hip/hip_bf16.h>
#include <math.h>

// Problem constants
#define BROWS 16384
#define IN_DIM 128
#define HID 512
#define ATT 256
#define KTOT 896          // IN_DIM + HID + ATT
#define KC_TOT 112        // KTOT / 8

typedef __bf16 bf16x8 __attribute__((ext_vector_type(8)));
typedef float f32x4 __attribute__((ext_vector_type(4)));

// ---------------------------------------------------------------------------
// Kernel 1: pack augmented weights -> B_stage[jt(8)][kc(112)][nl(192)][8] bf16.
// nl = jg*48 + type*16 + j16 ; jg in [0,4), type 0=gate 1=dyn 2=tau.
// j = jt*64 + jg*16 + j16. tau rows nonzero only for k in [128,640).
// ---------------------------------------------------------------------------
__device__ __forceinline__ float softplus_f(float x) {
    return fmaxf(x, 0.0f) + log1pf(__expf(-fabsf(x)));
}

__global__ void pack_B(const float* __restrict__ W_gd, const float* __restrict__ W_tau,
                       const float* __restrict__ gleak, const float* __restrict__ cm,
                       __hip_bfloat16* __restrict__ B_stage, float* __restrict__ dconst) {
    const int cid = blockIdx.x * 256 + threadIdx.x;   // 672*256 = 172032 exactly
    if (cid < HID) {
        dconst[cid] = softplus_f(cm[cid]) + softplus_f(gleak[cid]) + 1e-6f;
    }
    const int nl = cid % 192;
    const int kc = (cid / 192) % KC_TOT;
    const int jt = cid / (192 * KC_TOT);
    const int jg = nl / 48, type = (nl % 48) / 16, j16 = nl % 16;
    const int j = jt * 64 + jg * 16 + j16;
    const int k0 = kc * 8;

    float v[8];
    if (type == 0) {
        const float* s = W_gd + (size_t)j * KTOT + k0;
        #pragma unroll
        for (int i = 0; i < 8; ++i) v[i] = s[i];
    } else if (type == 1) {
        const float* s = W_gd + (size_t)(HID + j) * KTOT + k0;
        #pragma unroll
        for (int i = 0; i < 8; ++i) v[i] = s[i];
    } else {
        if (k0 >= IN_DIM && k0 < IN_DIM + HID) {
            const float* s = W_tau + (size_t)j * HID + (k0 - IN_DIM);
            #pragma unroll
            for (int i = 0; i < 8; ++i) v[i] = s[i];
        } else {
            #pragma unroll
            for (int i = 0; i < 8; ++i) v[i] = 0.0f;
        }
    }
    union { __hip_bfloat16 hh[8]; uint4 u; } p;
    #pragma unroll
    for (int i = 0; i < 8; ++i) p.hh[i] = __float2bfloat16(v[i]);
    *(uint4*)(B_stage + (size_t)cid * 8) = p.u;
}

// ---------------------------------------------------------------------------
// Kernel 2: fused convert+GEMM+epilogue.
// A (fp32, [x|h|ctx]) is loaded directly, converted to bf16 in-register, and
// ds_written into LDS with an XOR bank swizzle (mi ^ kc). fp32 loads for step
// ks+1 are issued after the barrier (overlap MFMA phase; they drain at the
// NEXT barrier, never extending this one).
// Block tile: 128(M) x 64(j) x {gate,dyn,tau}. 4 waves (2M x 2Jg). BK=64.
// Grid: 1024 blocks (mt = bx & 127 -> A-tile siblings co-XCD). 256 threads.
// LDS: As = 8kc x 128mi x 16B = 16KB ; Bs = 8kc x 192nl x 16B = 24KB.
// __launch_bounds__(256,2): unified VGPR+AGPR need is ~185 regs (96 acc AGPR
// + 32 prefetch + misc); (256,3) caps at ~170 and SPILLS TO SCRATCH (R3:
// WRITE_SIZE 177 MB). Do not raise.
// ---------------------------------------------------------------------------
__device__ __forceinline__ void slab_src(int ks, const float* x, const float* h,
                                         const float* c, const float*& src,
                                         int& rs, int& c0) {
    if (ks < 2)       { src = x; rs = IN_DIM; c0 = ks * 64; }
    else if (ks < 10) { src = h; rs = HID;    c0 = (ks - 2) * 64; }
    else              { src = c; rs = ATT;    c0 = (ks - 10) * 64; }
}

__global__ __launch_bounds__(256, 2) void ltc_gemm(
    const float* __restrict__ x, const float* __restrict__ h_ltc,
    const float* __restrict__ ctx, const __hip_bfloat16* __restrict__ B_stage,
    const float* __restrict__ b_gd, const float* __restrict__ b_tau,
    const float* __restrict__ dconst, float* __restrict__ out) {

    __shared__ __attribute__((aligned(16))) char smem[16384 + 24576];
    char* As = smem;
    char* Bs = smem + 16384;

    const int bx = blockIdx.x;
    const int mt = bx & 127;    // A-tile id; bx % 8 == mt % 8 -> co-XCD siblings
    const int jt = bx >> 7;     // 0..7
    const int tid = threadIdx.x;
    const int wave = tid >> 6, lane = tid & 63;
    const int wm = wave >> 1;   // 0..1  M half (64 rows)
    const int wj = wave & 1;    // 0..1  jg pair (32 j)
    const int q = lane >> 4, t = lane & 15;

    // A staging role: chunk (kc8, mi0 + 32r) for r<4
    const int kc8 = tid & 7;    // k-chunk in slab
    const int mi0 = tid >> 3;   // 0..31

    f32x4 accg[2][4], accd[2][4], acct[2][4];
    #pragma unroll
    for (int g = 0; g < 2; ++g)
        #pragma unroll
        for (int i = 0; i < 4; ++i) {
            accg[g][i] = (f32x4)0.0f; accd[g][i] = (f32x4)0.0f; acct[g][i] = (f32x4)0.0f;
        }

    // B staging: 24 chunks of 1KB, wave handles {wave+4r, r<6} via global_load_lds
    const __hip_bfloat16* bSrc[6]; char* bDst[6];
    #pragma unroll
    for (int r = 0; r < 6; ++r) {
        int c = wave + 4 * r;
        bSrc[r] = B_stage + (size_t)jt * (KC_TOT * 1536) + c * 512 + lane * 8;
        bDst[r] = Bs + c * 1024;
    }

    // Register prefetch of A slab ks=0 (fp32)
    float4 pf[4][2];
    {
        const float* src; int rs, c0;
        slab_src(0, x, h_ltc, ctx, src, rs, c0);
        #pragma unroll
        for (int r = 0; r < 4; ++r) {
            const float* p = src + (size_t)(mt * 128 + mi0 + 32 * r) * rs + c0 + kc8 * 8;
            pf[r][0] = *(const float4*)p;
            pf[r][1] = *(const float4*)(p + 4);
        }
    }

    for (int ks = 0; ks < 14; ++ks) {
        // Stage A: convert prefetched fp32 -> bf16, ds_write_b128 (XOR swizzle)
        #pragma unroll
        for (int r = 0; r < 4; ++r) {
            union { __hip_bfloat16 hh[8]; uint4 u; } pk;
            pk.hh[0] = __float2bfloat16(pf[r][0].x);
            pk.hh[1] = __float2bfloat16(pf[r][0].y);
            pk.hh[2] = __float2bfloat16(pf[r][0].z);
            pk.hh[3] = __float2bfloat16(pf[r][0].w);
            pk.hh[4] = __float2bfloat16(pf[r][1].x);
            pk.hh[5] = __float2bfloat16(pf[r][1].y);
            pk.hh[6] = __float2bfloat16(pf[r][1].z);
            pk.hh[7] = __float2bfloat16(pf[r][1].w);
            const int mi = mi0 + 32 * r;
            *(uint4*)(As + ((kc8 * 128 + (mi ^ kc8)) << 4)) = pk.u;
        }
        // Stage B: async global->LDS
        #pragma unroll
        for (int r = 0; r < 6; ++r)
            __builtin_amdgcn_global_load_lds(
                (const __attribute__((address_space(1))) void*)bSrc[r],
                (__attribute__((address_space(3))) void*)bDst[r], 16, 0, 0);
        __syncthreads();   // drains ds_write (lgkm) + B loads (vmcnt)

        // Register-prefetch A slab ks+1 (overlaps with MFMA phase below)
        if (ks < 13) {
            const float* src; int rs, c0;
            slab_src(ks + 1, x, h_ltc, ctx, src, rs, c0);
            #pragma unroll
            for (int r = 0; r < 4; ++r) {
                const float* p = src + (size_t)(mt * 128 + mi0 + 32 * r) * rs + c0 + kc8 * 8;
                pf[r][0] = *(const float4*)p;
                pf[r][1] = *(const float4*)(p + 4);
            }
        }

        const bool tau_on = (ks >= 2 && ks < 10);  // k in [128,640)
        #pragma unroll
        for (int ko2 = 0; ko2 < 2; ++ko2) {
            const int kcl = ko2 * 4 + q;
            const char* ab = As + ((kcl * 128 + ((wm * 64 + t) ^ kcl)) << 4);
            bf16x8 a0 = *(const bf16x8*)(ab);
            bf16x8 a1 = *(const bf16x8*)(ab + 256);
            bf16x8 a2 = *(const bf16x8*)(ab + 512);
            bf16x8 a3 = *(const bf16x8*)(ab + 768);
            #pragma unroll
            for (int g = 0; g < 2; ++g) {
                const char* bb = Bs + (((kcl * 192) + wj * 96 + g * 48 + t) << 4);
                bf16x8 bg = *(const bf16x8*)(bb);
                bf16x8 bd = *(const bf16x8*)(bb + 256);
                accg[g][0] = __builtin_amdgcn_mfma_f32_16x16x32_bf16(a0, bg, accg[g][0], 0, 0, 0);
                accg[g][1] = __builtin_amdgcn_mfma_f32_16x16x32_bf16(a1, bg, accg[g][1], 0, 0, 0);
                accg[g][2] = __builtin_amdgcn_mfma_f32_16x16x32_bf16(a2, bg, accg[g][2], 0, 0, 0);
                accg[g][3] = __builtin_amdgcn_mfma_f32_16x16x32_bf16(a3, bg, accg[g][3], 0, 0, 0);
                accd[g][0] = __builtin_amdgcn_mfma_f32_16x16x32_bf16(a0, bd, accd[g][0], 0, 0, 0);
                accd[g][1] = __builtin_amdgcn_mfma_f32_16x16x32_bf16(a1, bd, accd[g][1], 0, 0, 0);
                accd[g][2] = __builtin_amdgcn_mfma_f32_16x16x32_bf16(a2, bd, accd[g][2], 0, 0, 0);
                accd[g][3] = __builtin_amdgcn_mfma_f32_16x16x32_bf16(a3, bd, accd[g][3], 0, 0, 0);
                if (tau_on) {
                    bf16x8 bt = *(const bf16x8*)(bb + 512);
                    acct[g][0] = __builtin_amdgcn_mfma_f32_16x16x32_bf16(a0, bt, acct[g][0], 0, 0, 0);
                    acct[g][1] = __builtin_amdgcn_mfma_f32_16x16x32_bf16(a1, bt, acct[g][1], 0, 0, 0);
                    acct[g][2] = __builtin_amdgcn_mfma_f32_16x16x32_bf16(a2, bt, acct[g][2], 0, 0, 0);
                    acct[g][3] = __builtin_amdgcn_mfma_f32_16x16x32_bf16(a3, bt, acct[g][3], 0, 0, 0);
                }
            }
        }
        #pragma unroll
        for (int r = 0; r < 6; ++r) bSrc[r] += 12288;   // 8 kc * 192 * 8
        __syncthreads();   // protect LDS before next stage
    }

    // Epilogue: bias + sigmoid/tanh/softplus + divide, fast-math intrinsics.
    const int row0 = mt * 128 + wm * 64 + q * 4;
    #pragma unroll
    for (int g = 0; g < 2; ++g) {
        const int j = jt * 64 + (wj * 2 + g) * 16 + t;
        const float bgj = b_gd[j];
        const float bdj = b_gd[HID + j];
        const float btj = b_tau[j];
        const float dcj = dconst[j];
        #pragma unroll
        for (int i = 0; i < 4; ++i) {
            #pragma unroll
            for (int r = 0; r < 4; ++r) {
                const int row = row0 + i * 16 + r;
                const float gv = accg[g][i][r] + bgj;
                const float dv = accd[g][i][r] + bdj;
                const float tp = acct[g][i][r] + btj;
                const float hv = h_ltc[(size_t)row * HID + j];
                const float sig = __builtin_amdgcn_rcpf(1.0f + __expf(-gv));
                const float th  = 1.0f - 2.0f * __builtin_amdgcn_rcpf(__expf(2.0f * dv) + 1.0f);
                const float tau = fmaxf(tp, 0.0f) + __logf(1.0f + __expf(-fabsf(tp)));
                out[(size_t)row * HID + j] = (sig * th - hv) * __builtin_amdgcn_rcpf(tau + dcj);
            }
        }
    }
}

// ---------------------------------------------------------------------------
extern "C" void kernel_launch(void* const* d_in, const int* in_sizes, int n_in,
                              void* d_out, int out_size, void* d_ws, size_t ws_size,
                              hipStream_t stream) {
    // setup_inputs order: t, h_ltc, x_t, context, W_gd, b_gd, W_tau, b_tau, gleak, cm
    const float* h_ltc = (const float*)d_in[1];
    const float* x_t   = (const float*)d_in[2];
    const float* ctx   = (const float*)d_in[3];
    const float* W_gd  = (const float*)d_in[4];
    const float* b_gd  = (const float*)d_in[5];
    const float* W_tau = (const float*)d_in[6];
    const float* b_tau = (const float*)d_in[7];
    const float* gleak = (const float*)d_in[8];
    const float* cm    = (const float*)d_in[9];

    char* ws = (char*)d_ws;
    __hip_bfloat16* B_stage = (__hip_bfloat16*)ws;      // 8*112*192*8*2 = 2,752,512 B
    float* dconst = (float*)(ws + 2752512);             // 2,048 B

    pack_B<<<672, 256, 0, stream>>>(W_gd, W_tau, gleak, cm, B_stage, dconst);
    ltc_gemm<<<1024, 256, 0, stream>>>(x_t, h_ltc, ctx, B_stage, b_gd, b_tau, dconst,
                                       (float*)d_out);
}

// Round 5
// 169.030 us; speedup vs baseline: 1.4046x; 1.0067x over previous
//
#include <hip/hip_runtime.h>
#include <hip/hip_bf16.h>
#include <math.h>

// Problem constants
#define BROWS 16384
#define IN_DIM 128
#define HID 512
#define ATT 256
#define KTOT 896          // IN_DIM + HID + ATT
#define KC_TOT 112        // KTOT / 8

typedef __bf16 bf16x8 __attribute__((ext_vector_type(8)));
typedef float f32x4 __attribute__((ext_vector_type(4)));

// ---------------------------------------------------------------------------
// Kernel 1: pack augmented weights -> B_stage[jt(8)][kc(112)][nl(192)][8] bf16.
// nl = jg*48 + type*16 + j16 ; jg in [0,4), type 0=gate 1=dyn 2=tau.
// j = jt*64 + jg*16 + j16. tau rows nonzero only for k in [128,640).
// ---------------------------------------------------------------------------
__device__ __forceinline__ float softplus_f(float x) {
    return fmaxf(x, 0.0f) + log1pf(__expf(-fabsf(x)));
}

__global__ void pack_B(const float* __restrict__ W_gd, const float* __restrict__ W_tau,
                       const float* __restrict__ gleak, const float* __restrict__ cm,
                       __hip_bfloat16* __restrict__ B_stage, float* __restrict__ dconst) {
    const int cid = blockIdx.x * 256 + threadIdx.x;   // 672*256 = 172032 exactly
    if (cid < HID) {
        dconst[cid] = softplus_f(cm[cid]) + softplus_f(gleak[cid]) + 1e-6f;
    }
    const int nl = cid % 192;
    const int kc = (cid / 192) % KC_TOT;
    const int jt = cid / (192 * KC_TOT);
    const int jg = nl / 48, type = (nl % 48) / 16, j16 = nl % 16;
    const int j = jt * 64 + jg * 16 + j16;
    const int k0 = kc * 8;

    float v[8];
    if (type == 0) {
        const float* s = W_gd + (size_t)j * KTOT + k0;
        #pragma unroll
        for (int i = 0; i < 8; ++i) v[i] = s[i];
    } else if (type == 1) {
        const float* s = W_gd + (size_t)(HID + j) * KTOT + k0;
        #pragma unroll
        for (int i = 0; i < 8; ++i) v[i] = s[i];
    } else {
        if (k0 >= IN_DIM && k0 < IN_DIM + HID) {
            const float* s = W_tau + (size_t)j * HID + (k0 - IN_DIM);
            #pragma unroll
            for (int i = 0; i < 8; ++i) v[i] = s[i];
        } else {
            #pragma unroll
            for (int i = 0; i < 8; ++i) v[i] = 0.0f;
        }
    }
    union { __hip_bfloat16 hh[8]; uint4 u; } p;
    #pragma unroll
    for (int i = 0; i < 8; ++i) p.hh[i] = __float2bfloat16(v[i]);
    *(uint4*)(B_stage + (size_t)cid * 8) = p.u;
}

// ---------------------------------------------------------------------------
// Kernel 2: fused convert+GEMM+epilogue, 8-wave blocks for occupancy.
// Block: 512 threads (8 waves), tile 128(M) x 64(j) x {gate,dyn,tau}, BK=64.
// Wave split: wm = wave>>2 (M half), wj = wave&3 (16-j group). Per-wave acc =
// 4 m-frags x 3 types = 48 regs; total ~115/wave -> __launch_bounds__(512,4)
// (cap 128) -> 2 blocks/CU = 4 waves/SIMD resident (R4 had 2: latency-bound,
// Occupancy 18.8%). LDS unchanged: As 16KB + Bs 24KB = 40KB -> 2 blocks/CU.
// R3 lesson: over-tight launch_bounds spills acc to scratch (WRITE 177MB) —
// if WRITE_SIZE spikes, trim regs, don't raise waves.
// ---------------------------------------------------------------------------
__device__ __forceinline__ void slab_src(int ks, const float* x, const float* h,
                                         const float* c, const float*& src,
                                         int& rs, int& c0) {
    if (ks < 2)       { src = x; rs = IN_DIM; c0 = ks * 64; }
    else if (ks < 10) { src = h; rs = HID;    c0 = (ks - 2) * 64; }
    else              { src = c; rs = ATT;    c0 = (ks - 10) * 64; }
}

__global__ __launch_bounds__(512, 4) void ltc_gemm(
    const float* __restrict__ x, const float* __restrict__ h_ltc,
    const float* __restrict__ ctx, const __hip_bfloat16* __restrict__ B_stage,
    const float* __restrict__ b_gd, const float* __restrict__ b_tau,
    const float* __restrict__ dconst, float* __restrict__ out) {

    __shared__ __attribute__((aligned(16))) char smem[16384 + 24576];
    char* As = smem;
    char* Bs = smem + 16384;

    const int bx = blockIdx.x;
    const int mt = bx & 127;    // A-tile id; bx % 8 == mt % 8 -> co-XCD siblings
    const int jt = bx >> 7;     // 0..7
    const int tid = threadIdx.x;
    const int wave = tid >> 6, lane = tid & 63;
    const int wm = wave >> 2;   // 0..1  M half (64 rows)
    const int wj = wave & 3;    // 0..3  16-j group
    const int q = lane >> 4, t = lane & 15;

    // A staging role: thread stages chunks (kc8, mi0 + 64r), r<2
    const int kc8 = tid & 7;    // k-chunk in slab
    const int mi0 = tid >> 3;   // 0..63

    f32x4 accg[4], accd[4], acct[4];
    #pragma unroll
    for (int i = 0; i < 4; ++i) {
        accg[i] = (f32x4)0.0f; accd[i] = (f32x4)0.0f; acct[i] = (f32x4)0.0f;
    }

    // B staging: 24 chunks of 1KB, wave handles {wave+8r, r<3} via global_load_lds
    const __hip_bfloat16* bSrc[3]; char* bDst[3];
    #pragma unroll
    for (int r = 0; r < 3; ++r) {
        int c = wave + 8 * r;
        bSrc[r] = B_stage + (size_t)jt * (KC_TOT * 1536) + c * 512 + lane * 8;
        bDst[r] = Bs + c * 1024;
    }

    // Register prefetch of A slab ks=0 (fp32)
    float4 pf[2][2];
    {
        const float* src; int rs, c0;
        slab_src(0, x, h_ltc, ctx, src, rs, c0);
        #pragma unroll
        for (int r = 0; r < 2; ++r) {
            const float* p = src + (size_t)(mt * 128 + mi0 + 64 * r) * rs + c0 + kc8 * 8;
            pf[r][0] = *(const float4*)p;
            pf[r][1] = *(const float4*)(p + 4);
        }
    }

    for (int ks = 0; ks < 14; ++ks) {
        // Stage B first: async global->LDS (vmcnt latency overlaps A converts)
        #pragma unroll
        for (int r = 0; r < 3; ++r)
            __builtin_amdgcn_global_load_lds(
                (const __attribute__((address_space(1))) void*)bSrc[r],
                (__attribute__((address_space(3))) void*)bDst[r], 16, 0, 0);
        // Stage A: convert prefetched fp32 -> bf16, ds_write_b128 (XOR swizzle)
        #pragma unroll
        for (int r = 0; r < 2; ++r) {
            union { __hip_bfloat16 hh[8]; uint4 u; } pk;
            pk.hh[0] = __float2bfloat16(pf[r][0].x);
            pk.hh[1] = __float2bfloat16(pf[r][0].y);
            pk.hh[2] = __float2bfloat16(pf[r][0].z);
            pk.hh[3] = __float2bfloat16(pf[r][0].w);
            pk.hh[4] = __float2bfloat16(pf[r][1].x);
            pk.hh[5] = __float2bfloat16(pf[r][1].y);
            pk.hh[6] = __float2bfloat16(pf[r][1].z);
            pk.hh[7] = __float2bfloat16(pf[r][1].w);
            const int mi = mi0 + 64 * r;
            *(uint4*)(As + ((kc8 * 128 + (mi ^ kc8)) << 4)) = pk.u;
        }
        __syncthreads();   // drains ds_write (lgkm) + B loads (vmcnt)

        // Register-prefetch A slab ks+1 (drains at NEXT barrier, not this one)
        if (ks < 13) {
            const float* src; int rs, c0;
            slab_src(ks + 1, x, h_ltc, ctx, src, rs, c0);
            #pragma unroll
            for (int r = 0; r < 2; ++r) {
                const float* p = src + (size_t)(mt * 128 + mi0 + 64 * r) * rs + c0 + kc8 * 8;
                pf[r][0] = *(const float4*)p;
                pf[r][1] = *(const float4*)(p + 4);
            }
        }

        const bool tau_on = (ks >= 2 && ks < 10);  // k in [128,640)
        #pragma unroll
        for (int ko2 = 0; ko2 < 2; ++ko2) {
            const int kcl = ko2 * 4 + q;
            const char* ab = As + ((kcl * 128 + ((wm * 64 + t) ^ kcl)) << 4);
            bf16x8 a0 = *(const bf16x8*)(ab);
            bf16x8 a1 = *(const bf16x8*)(ab + 256);
            bf16x8 a2 = *(const bf16x8*)(ab + 512);
            bf16x8 a3 = *(const bf16x8*)(ab + 768);
            const char* bb = Bs + (((kcl * 192) + wj * 48 + t) << 4);
            bf16x8 bg = *(const bf16x8*)(bb);
            bf16x8 bd = *(const bf16x8*)(bb + 256);
            accg[0] = __builtin_amdgcn_mfma_f32_16x16x32_bf16(a0, bg, accg[0], 0, 0, 0);
            accg[1] = __builtin_amdgcn_mfma_f32_16x16x32_bf16(a1, bg, accg[1], 0, 0, 0);
            accg[2] = __builtin_amdgcn_mfma_f32_16x16x32_bf16(a2, bg, accg[2], 0, 0, 0);
            accg[3] = __builtin_amdgcn_mfma_f32_16x16x32_bf16(a3, bg, accg[3], 0, 0, 0);
            accd[0] = __builtin_amdgcn_mfma_f32_16x16x32_bf16(a0, bd, accd[0], 0, 0, 0);
            accd[1] = __builtin_amdgcn_mfma_f32_16x16x32_bf16(a1, bd, accd[1], 0, 0, 0);
            accd[2] = __builtin_amdgcn_mfma_f32_16x16x32_bf16(a2, bd, accd[2], 0, 0, 0);
            accd[3] = __builtin_amdgcn_mfma_f32_16x16x32_bf16(a3, bd, accd[3], 0, 0, 0);
            if (tau_on) {
                bf16x8 bt = *(const bf16x8*)(bb + 512);
                acct[0] = __builtin_amdgcn_mfma_f32_16x16x32_bf16(a0, bt, acct[0], 0, 0, 0);
                acct[1] = __builtin_amdgcn_mfma_f32_16x16x32_bf16(a1, bt, acct[1], 0, 0, 0);
                acct[2] = __builtin_amdgcn_mfma_f32_16x16x32_bf16(a2, bt, acct[2], 0, 0, 0);
                acct[3] = __builtin_amdgcn_mfma_f32_16x16x32_bf16(a3, bt, acct[3], 0, 0, 0);
            }
        }
        #pragma unroll
        for (int r = 0; r < 3; ++r) bSrc[r] += 12288;   // 8 kc * 192 * 8
        __syncthreads();   // protect LDS before next stage
    }

    // Epilogue: bias + sigmoid/tanh/softplus + divide, fast-math intrinsics.
    const int row0 = mt * 128 + wm * 64 + q * 4;
    const int j = jt * 64 + wj * 16 + t;
    const float bgj = b_gd[j];
    const float bdj = b_gd[HID + j];
    const float btj = b_tau[j];
    const float dcj = dconst[j];
    #pragma unroll
    for (int i = 0; i < 4; ++i) {
        #pragma unroll
        for (int r = 0; r < 4; ++r) {
            const int row = row0 + i * 16 + r;
            const float gv = accg[i][r] + bgj;
            const float dv = accd[i][r] + bdj;
            const float tp = acct[i][r] + btj;
            const float hv = h_ltc[(size_t)row * HID + j];
            const float sig = __builtin_amdgcn_rcpf(1.0f + __expf(-gv));
            const float th  = 1.0f - 2.0f * __builtin_amdgcn_rcpf(__expf(2.0f * dv) + 1.0f);
            const float tau = fmaxf(tp, 0.0f) + __logf(1.0f + __expf(-fabsf(tp)));
            out[(size_t)row * HID + j] = (sig * th - hv) * __builtin_amdgcn_rcpf(tau + dcj);
        }
    }
}

// ---------------------------------------------------------------------------
extern "C" void kernel_launch(void* const* d_in, const int* in_sizes, int n_in,
                              void* d_out, int out_size, void* d_ws, size_t ws_size,
                              hipStream_t stream) {
    // setup_inputs order: t, h_ltc, x_t, context, W_gd, b_gd, W_tau, b_tau, gleak, cm
    const float* h_ltc = (const float*)d_in[1];
    const float* x_t   = (const float*)d_in[2];
    const float* ctx   = (const float*)d_in[3];
    const float* W_gd  = (const float*)d_in[4];
    const float* b_gd  = (const float*)d_in[5];
    const float* W_tau = (const float*)d_in[6];
    const float* b_tau = (const float*)d_in[7];
    const float* gleak = (const float*)d_in[8];
    const float* cm    = (const float*)d_in[9];

    char* ws = (char*)d_ws;
    __hip_bfloat16* B_stage = (__hip_bfloat16*)ws;      // 8*112*192*8*2 = 2,752,512 B
    float* dconst = (float*)(ws + 2752512);             // 2,048 B

    pack_B<<<672, 256, 0, stream>>>(W_gd, W_tau, gleak, cm, B_stage, dconst);
    ltc_gemm<<<1024, 512, 0, stream>>>(x_t, h_ltc, ctx, B_stage, b_gd, b_tau, dconst,
                                       (float*)d_out);
}